// Round 15
// baseline (111.616 us; speedup 1.0000x reference)
//
#include <hip/hip_runtime.h>

#define NB 8
#define NN 128
#define ND 64
#define NE 3
#define NH 256
#define NOUT 64

typedef short bf16x8_t __attribute__((ext_vector_type(8)));
typedef float f32x4_t __attribute__((ext_vector_type(4)));
typedef unsigned short ushort_t;

static __device__ __forceinline__ unsigned short f2bf(float f) {
    unsigned u = __float_as_uint(f);
    u += 0x7FFFu + ((u >> 16) & 1u);
    return (unsigned short)(u >> 16);
}
static __device__ __forceinline__ unsigned pk2bf(float a, float b) {
    return (unsigned)f2bf(a) | ((unsigned)f2bf(b) << 16);
}

// A-fragment gen from f32 P,Q: relu(P+Q) -> bf16 pack (8 add + 8 max + 4 pack)
static __device__ __forceinline__ bf16x8_t a_genf(float4 p0, float4 p1, float4 q0, float4 q1) {
    union { uint4 u; bf16x8_t v; } r;
    r.u.x = pk2bf(fmaxf(p0.x + q0.x, 0.f), fmaxf(p0.y + q0.y, 0.f));
    r.u.y = pk2bf(fmaxf(p0.z + q0.z, 0.f), fmaxf(p0.w + q0.w, 0.f));
    r.u.z = pk2bf(fmaxf(p1.x + q1.x, 0.f), fmaxf(p1.y + q1.y, 0.f));
    r.u.w = pk2bf(fmaxf(p1.z + q1.z, 0.f), fmaxf(p1.w + q1.w, 0.f));
    return r.v;
}

// ============ Kernel 1: We2p pack (0..47) + P/Q f32 (48..239) + edge pack (240..1263) ============
// We2p layout (ushorts): [((e*16 + nf)*8 + kk)*512 + lane*8 + jj]
//   = bf16(We2[e][k = kk*32 + (lane>>4)*8 + jj][n = nf*16 + (lane&15)])
#define IT 16
__global__ __launch_bounds__(256) void prep_kernel(
    const float* __restrict__ We2, const float* __restrict__ ns,
    const float* __restrict__ We1, const float* __restrict__ be1,
    const float* __restrict__ edges,
    ushort_t* __restrict__ We2p,
    float* __restrict__ P, float* __restrict__ Q,
    ushort_t* __restrict__ list_ws, int4* __restrict__ cnts_ws)
{
    const int t = threadIdx.x;
    const int blk = blockIdx.x;

    if (blk < 48) {             // ---- We2p fragment pack ----
        __shared__ float slab[256][16];
        const int e = blk >> 4, nfg = blk & 15;
        const int n0 = nfg * 16;
#pragma unroll
        for (int it = 0; it < 16; it++) {
            const int k = (t >> 4) + it * 16;
            slab[k][t & 15] = We2[((size_t)e * NH + k) * NH + n0 + (t & 15)];
        }
        __syncthreads();
        ushort_t* dst = We2p + ((size_t)e * 16 + nfg) * 4096;
#pragma unroll
        for (int it = 0; it < 16; it++) {
            const int idx = it * 256 + t;
            const int kk = idx >> 9;
            const int ln = (idx >> 3) & 63;
            const int jj = idx & 7;
            const int k = kk * 32 + (ln >> 4) * 8 + jj;
            dst[idx] = f2bf(slab[k][ln & 15]);
        }
        return;
    }
    if (blk < 240) {            // ---- P/Q precompute -> f32 ----
        __shared__ float ns_lds[IT][ND];
        const int blk2 = blk - 48;
        const int itile = blk2 & 7;
        const int e = (blk2 >> 3) % NE;
        const int b = blk2 / 24;
        const int i0 = itile * IT;
        for (int x = t; x < IT * ND; x += 256)
            ns_lds[x / ND][x % ND] = ns[(size_t)(b * NN + i0 + x / ND) * ND + (x % ND)];
        __syncthreads();
        const int h = t;
        float accP[IT], accQ[IT];
        const float bias = be1[e * NH + h];
#pragma unroll
        for (int m = 0; m < IT; m++) { accP[m] = 0.f; accQ[m] = bias; }
        const float* W1 = We1 + (size_t)e * 2 * ND * NH + h;
        for (int d = 0; d < ND; d++) {
            const float w1 = W1[(size_t)d * NH];
            const float w2 = W1[(size_t)(ND + d) * NH];
#pragma unroll
            for (int m = 0; m < IT; m++) {
                accP[m] = fmaf(ns_lds[m][d], w1, accP[m]);
                accQ[m] = fmaf(ns_lds[m][d], w2, accQ[m]);
            }
        }
#pragma unroll
        for (int m = 0; m < IT; m++) {
            const size_t idx = ((size_t)((b * NE + e) * NN) + i0 + m) * NH + h;
            P[idx] = accP[m];
            Q[idx] = accQ[m];
        }
        return;
    }
    // ---- edge pack: per (b,j): bucketed source lists by edge type ----
    {
        __shared__ unsigned long long wm[2][NE];
        const int pb = blk - 240;
        const int b = pb >> 7, j = pb & 127;
        const int lane = t & 63, wave = t >> 6;
        int ecls = -1;
        if (t < 128) {
            const float4 ev = *(const float4*)(edges + ((size_t)(b * NN + t) * NN + j) * 4);
            ecls = ev.y > 0.5f ? 0 : (ev.z > 0.5f ? 1 : (ev.w > 0.5f ? 2 : -1));
#pragma unroll
            for (int ee = 0; ee < NE; ee++) {
                unsigned long long m = __ballot(ecls == ee);
                if (lane == 0) wm[wave][ee] = m;
            }
        }
        __syncthreads();
        const int c0 = __popcll(wm[0][0]) + __popcll(wm[1][0]);
        const int c1 = __popcll(wm[0][1]) + __popcll(wm[1][1]);
        const int c2 = __popcll(wm[0][2]) + __popcll(wm[1][2]);
        if (t < 128 && ecls >= 0) {
            const unsigned long long lower = (1ull << lane) - 1ull;
            int pos = __popcll(wm[wave][ecls] & lower);
            if (wave == 1) pos += __popcll(wm[0][ecls]);
            pos += (ecls > 0 ? c0 : 0) + (ecls > 1 ? c1 : 0);
            list_ws[(size_t)pb * NN + pos] = (ushort_t)t;
        }
        if (t == 0) { int4 cc; cc.x = c0; cc.y = c1; cc.z = c2; cc.w = 0; cnts_ws[pb] = cc; }
    }
}

// ============ Kernel 2: half-B-LDS GEMM; block = (b,e, 8 j's, 128-col half); wave = j-pair ============
__global__ __launch_bounds__(256) void gemm_kernel(
    const float* __restrict__ Pf,
    const float* __restrict__ Qf,
    const ushort_t* __restrict__ We2p,
    const float* __restrict__ be2,
    const ushort_t* __restrict__ list_ws,
    const int4* __restrict__ cnts_ws,
    float* __restrict__ aggr3)
{
    // grid: 768 = b(8) x e(3) x jg(16) x nh(2); 4 waves; wave owns j-pair {jg*8+wave*2, +1}
    const int blk = blockIdx.x;
    const int nh = blk & 1;
    const int jg = (blk >> 1) & 15;
    const int e  = (blk >> 5) % 3;
    const int b  = blk / 96;
    const int tid = threadIdx.x;
    const int lane = tid & 63;
    const int wave = tid >> 6;

    __shared__ __align__(16) ushort_t Bl[8 * 8 * 512];   // 64 KB: [nf][kk][512]

    {   // ---- one-time B stage: linear 64 KB L2 -> LDS, fully coalesced ----
        const ushort_t* Bsrc = We2p + ((size_t)e * 16 + nh * 8) * 4096;
#pragma unroll
        for (int it = 0; it < 16; it++) {
            const int o = it * 2048 + tid * 8;
            *(uint4*)&Bl[o] = *(const uint4*)&Bsrc[o];
        }
    }

    const int j0 = jg * 8 + wave * 2;
    const int j1 = j0 + 1;
    const int4 cc0 = cnts_ws[b * NN + j0];
    const int4 cc1 = cnts_ws[b * NN + j1];
    const int ce0 = e == 0 ? cc0.x : (e == 1 ? cc0.y : cc0.z);
    const int ce1 = e == 0 ? cc1.x : (e == 1 ? cc1.y : cc1.z);
    const int st0 = (e > 0 ? cc0.x : 0) + (e > 1 ? cc0.y : 0);
    const int st1 = (e > 0 ? cc1.x : 0) + (e > 1 ? cc1.y : 0);
    const ushort_t* L0 = list_ws + (size_t)(b * NN + j0) * NN + st0;
    const ushort_t* L1 = list_ws + (size_t)(b * NN + j1) * NN + st1;
    const float* Q0 = Qf + (size_t)((b * NE + e) * NN + j0) * NH;
    const float* Q1 = Qf + (size_t)((b * NE + e) * NN + j1) * NH;
    const float* Pb = Pf + (size_t)(b * NE + e) * NN * NH;

    float bb[8];
#pragma unroll
    for (int nf = 0; nf < 8; nf++)
        bb[nf] = be2[e * NH + nh * 128 + nf * 16 + (lane & 15)];

    __syncthreads();   // Bl visible; only barrier

    float rs0[8], rs1[8];
#pragma unroll
    for (int nf = 0; nf < 8; nf++) { rs0[nf] = 0.f; rs1[nf] = 0.f; }

    const int cemax = ce0 > ce1 ? ce0 : ce1;
    if (cemax > 0) {
        const int F = (cemax + 15) >> 4;
        for (int f = 0; f < F; f++) {
            const int lm = f * 16 + (lane & 15);
            const int q0i = lm < ce0 ? lm : (ce0 > 0 ? ce0 - 1 : 0);
            const int q1i = lm < ce1 ? lm : (ce1 > 0 ? ce1 - 1 : 0);
            const int row0 = ce0 > 0 ? L0[q0i] : 0;    // guard: never index unwritten list slots
            const int row1 = ce1 > 0 ? L1[q1i] : 0;
            const float* P0 = Pb + (size_t)row0 * NH;
            const float* P1 = Pb + (size_t)row1 * NH;

            f32x4_t a0c[8], a1c[8];
            const f32x4_t z4 = {0.f, 0.f, 0.f, 0.f};
#pragma unroll
            for (int nf = 0; nf < 8; nf++) { a0c[nf] = z4; a1c[nf] = z4; }

#pragma unroll 2
            for (int kk = 0; kk < 8; kk++) {
                const int ko = kk * 32 + (lane >> 4) * 8;
                const bf16x8_t af0 = a_genf(*(const float4*)(P0 + ko), *(const float4*)(P0 + ko + 4),
                                            *(const float4*)(Q0 + ko), *(const float4*)(Q0 + ko + 4));
                const bf16x8_t af1 = a_genf(*(const float4*)(P1 + ko), *(const float4*)(P1 + ko + 4),
                                            *(const float4*)(Q1 + ko), *(const float4*)(Q1 + ko + 4));
#pragma unroll
                for (int nf = 0; nf < 8; nf++) {
                    // one B-fragment feeds both j's MFMAs
                    const bf16x8_t bfr = *(const bf16x8_t*)(&Bl[(nf * 8 + kk) * 512 + lane * 8]);
                    a0c[nf] = __builtin_amdgcn_mfma_f32_16x16x32_bf16(af0, bfr, a0c[nf], 0, 0, 0);
                    a1c[nf] = __builtin_amdgcn_mfma_f32_16x16x32_bf16(af1, bfr, a1c[nf], 0, 0, 0);
                }
            }
            // epilogue: bias+relu+row-mask, cross-lane col reduce
#pragma unroll
            for (int nf = 0; nf < 8; nf++) {
                float s0 = 0.f, s1 = 0.f;
#pragma unroll
                for (int r = 0; r < 4; r++) {
                    const int pos = f * 16 + ((lane >> 4) << 2) + r;
                    if (pos < ce0) s0 += fmaxf(a0c[nf][r] + bb[nf], 0.f);
                    if (pos < ce1) s1 += fmaxf(a1c[nf][r] + bb[nf], 0.f);
                }
                s0 += __shfl_xor(s0, 16, 64);
                s0 += __shfl_xor(s0, 32, 64);
                s1 += __shfl_xor(s1, 16, 64);
                s1 += __shfl_xor(s1, 32, 64);
                if (lane < 16) { rs0[nf] += s0; rs1[nf] += s1; }
            }
        }
    }
    // direct stores (unique writer per (b,e,j,col); ce==0 writes zeros)
    if (lane < 16) {
        float* d0 = aggr3 + (size_t)((b * NE + e) * NN + j0) * NH + nh * 128 + lane;
        float* d1 = aggr3 + (size_t)((b * NE + e) * NN + j1) * NH + nh * 128 + lane;
#pragma unroll
        for (int nf = 0; nf < 8; nf++) { d0[nf * 16] = rs0[nf]; d1[nf * 16] = rs1[nf]; }
    }
}

// ============ Kernel 3: decoder, 8 j's per block (weight reuse x8) ============
__global__ __launch_bounds__(256) void dec_kernel(
    const float* __restrict__ ns,
    const float* __restrict__ aggr3,
    const float* __restrict__ Wd1, const float* __restrict__ bd1,
    const float* __restrict__ Wd2, const float* __restrict__ bd2,
    float* __restrict__ out)
{
    const int b = blockIdx.x >> 4;
    const int jg = blockIdx.x & 15;
    const int tid = threadIdx.x;
    __shared__ __align__(16) float xs[8][320];
    __shared__ __align__(16) float o1s[8][NH];

    // stage x = [ns(64) | sum_e aggr3(256)] for 8 j's
    for (int x = tid; x < 8 * 320; x += 256) {
        const int jj = x / 320, k = x % 320;
        const int j = jg * 8 + jj;
        float v;
        if (k < ND) v = ns[(size_t)(b * NN + j) * ND + k];
        else {
            const int c = k - ND;
            v = aggr3[(size_t)((b * NE + 0) * NN + j) * NH + c]
              + aggr3[(size_t)((b * NE + 1) * NN + j) * NH + c]
              + aggr3[(size_t)((b * NE + 2) * NN + j) * NH + c];
        }
        xs[jj][k] = v;
    }
    __syncthreads();
    // layer 1: thread owns col n; 8 j's share each weight load
    {
        const int n = tid;
        float acc[8];
        const float b1 = bd1[n];
#pragma unroll
        for (int jj = 0; jj < 8; jj++) acc[jj] = b1;
        for (int k4 = 0; k4 < 80; k4++) {
            const float w0 = Wd1[(size_t)(k4 * 4 + 0) * NH + n];
            const float w1 = Wd1[(size_t)(k4 * 4 + 1) * NH + n];
            const float w2 = Wd1[(size_t)(k4 * 4 + 2) * NH + n];
            const float w3 = Wd1[(size_t)(k4 * 4 + 3) * NH + n];
#pragma unroll
            for (int jj = 0; jj < 8; jj++) {
                const float4 xv = *(const float4*)(&xs[jj][k4 * 4]);
                acc[jj] = fmaf(xv.x, w0, fmaf(xv.y, w1, fmaf(xv.z, w2, fmaf(xv.w, w3, acc[jj]))));
            }
        }
#pragma unroll
        for (int jj = 0; jj < 8; jj++) o1s[jj][n] = fmaxf(acc[jj], 0.f);
    }
    __syncthreads();
    // layer 2: thread = (jj, 2 cols)
    {
        const int jj = tid >> 5, cp = tid & 31;
        const int n0 = cp * 2;
        float a0 = bd2[n0], a1 = bd2[n0 + 1];
        for (int h4 = 0; h4 < 64; h4++) {
            const float4 ov = *(const float4*)(&o1s[jj][h4 * 4]);
            a0 = fmaf(ov.x, Wd2[(size_t)(h4 * 4 + 0) * NOUT + n0], a0);
            a1 = fmaf(ov.x, Wd2[(size_t)(h4 * 4 + 0) * NOUT + n0 + 1], a1);
            a0 = fmaf(ov.y, Wd2[(size_t)(h4 * 4 + 1) * NOUT + n0], a0);
            a1 = fmaf(ov.y, Wd2[(size_t)(h4 * 4 + 1) * NOUT + n0 + 1], a1);
            a0 = fmaf(ov.z, Wd2[(size_t)(h4 * 4 + 2) * NOUT + n0], a0);
            a1 = fmaf(ov.z, Wd2[(size_t)(h4 * 4 + 2) * NOUT + n0 + 1], a1);
            a0 = fmaf(ov.w, Wd2[(size_t)(h4 * 4 + 3) * NOUT + n0], a0);
            a1 = fmaf(ov.w, Wd2[(size_t)(h4 * 4 + 3) * NOUT + n0 + 1], a1);
        }
        const int j = jg * 8 + jj;
        out[(size_t)(b * NN + j) * NOUT + n0] = fmaxf(a0, 0.f);
        out[(size_t)(b * NN + j) * NOUT + n0 + 1] = fmaxf(a1, 0.f);
    }
}

extern "C" void kernel_launch(void* const* d_in, const int* in_sizes, int n_in,
                              void* d_out, int out_size, void* d_ws, size_t ws_size,
                              hipStream_t stream)
{
    const float* ns    = (const float*)d_in[0];
    const float* edges = (const float*)d_in[1];
    const float* We1   = (const float*)d_in[2];
    const float* be1   = (const float*)d_in[3];
    const float* We2   = (const float*)d_in[4];
    const float* be2   = (const float*)d_in[5];
    const float* Wd1   = (const float*)d_in[6];
    const float* bd1   = (const float*)d_in[7];
    const float* Wd2   = (const float*)d_in[8];
    const float* bd2   = (const float*)d_in[9];
    float* outp = (float*)d_out;

    // ws layout (~10.2 MB)
    float* Pf = (float*)d_ws;                               // 786432 f32
    float* Qf = Pf + (size_t)NB * NE * NN * NH;             // 786432 f32
    ushort_t* We2p = (ushort_t*)(Qf + (size_t)NB * NE * NN * NH); // 196608 us
    ushort_t* list_ws = We2p + (size_t)NE * NH * NH;        // 131072 us
    int4* cnts_ws = (int4*)(list_ws + (size_t)NB * NN * NN);// 1024 int4
    float* aggr3 = (float*)(cnts_ws + NB * NN);             // 786432 f32

    hipLaunchKernelGGL(prep_kernel, dim3(1264), dim3(256), 0, stream,
                       We2, ns, We1, be1, edges, We2p, Pf, Qf, list_ws, cnts_ws);
    hipLaunchKernelGGL(gemm_kernel, dim3(768), dim3(256), 0, stream,
                       Pf, Qf, We2p, be2, list_ws, cnts_ws, aggr3);
    hipLaunchKernelGGL(dec_kernel, dim3(NB * 16), dim3(256), 0, stream,
                       ns, aggr3, Wd1, bd1, Wd2, bd2, outp);
}